// Round 13
// baseline (185.157 us; speedup 1.0000x reference)
//
#include <hip/hip_runtime.h>
#include <hip/hip_fp16.h>

#define NN 50000
#define NE 800000
#define D 64
#define GB ((NN + 63) / 64)       // 782 gemm tiles
#define GH 391                    // gemm1 split: half with bin, half with sort
#define NBUCK ((NN + 127) >> 7)   // 391 buckets of 128 dst nodes
#define CHUNK 4096
#define EBLKS ((NE + CHUNK - 1) / CHUNK)   // 196 bin blocks
#define CAPB 4096                 // per-bucket capacity (mean 2046, sd 45 -> +45 sigma)
#define ARENA_BYTES (16384 + 17408 + 4352 + 4352)

__device__ __forceinline__ float lrelu(float s) { return (s > 0.0f) ? s : 0.2f * s; }

// ---------------- CSR bodies --------------------------------------------------

__device__ __forceinline__ void bin_body(int blk, const int* __restrict__ ei,
                                         int* __restrict__ gcur,
                                         unsigned* __restrict__ pairs, char* arena) {
  int* cnt_loc = (int*)arena;            // NBUCK
  int* base_loc = cnt_loc + NBUCK;       // NBUCK
  int t = threadIdx.x;
  int e0 = blk * CHUNK;
  int n = (NE - e0 < CHUNK) ? (NE - e0) : CHUNK;
  int nv = n >> 2;
  const int4* d4 = (const int4*)(ei + NE + e0);
  const int4* s4 = (const int4*)(ei + e0);
  for (int i = t; i < NBUCK; i += 256) cnt_loc[i] = 0;
  __syncthreads();
  for (int i = t; i < nv; i += 256) {
    int4 v = d4[i];
    atomicAdd(&cnt_loc[v.x >> 7], 1);
    atomicAdd(&cnt_loc[v.y >> 7], 1);
    atomicAdd(&cnt_loc[v.z >> 7], 1);
    atomicAdd(&cnt_loc[v.w >> 7], 1);
  }
  __syncthreads();
  for (int i = t; i < NBUCK; i += 256) {
    int c = cnt_loc[i];
    base_loc[i] = c ? (i * CAPB + atomicAdd(&gcur[i], c)) : 0;
    cnt_loc[i] = 0;
  }
  __syncthreads();
  for (int i = t; i < nv; i += 256) {
    int4 sv = s4[i];
    int4 dv = d4[i];
#pragma unroll
    for (int e = 0; e < 4; ++e) {
      int src = (&sv.x)[e];
      int dst = (&dv.x)[e];
      int b = dst >> 7;
      int off = atomicAdd(&cnt_loc[b], 1);
      unsigned pk = ((unsigned)src << 7) | (unsigned)(dst & 127);
      __builtin_nontemporal_store(pk, &pairs[base_loc[b] + off]);
    }
  }
}

__device__ __forceinline__ void sort_body(int b, const unsigned* __restrict__ pairs,
                                          const int* __restrict__ gcur,
                                          int* __restrict__ row_start,
                                          int* __restrict__ deg,
                                          int* __restrict__ sorted_src, char* arena) {
  int* cnt = (int*)arena;        // 128
  int* exc = cnt + 128;          // 128
  int* cur = exc + 128;          // 128
  int* buf = cur + 128;          // CAPB
  int t = threadIdx.x;
  int n0 = b << 7;
  int start = b * CAPB;
  int cntb = gcur[b];
  if (cntb > CAPB) cntb = CAPB;
  int nv = cntb >> 2;
  const uint4* p4 = (const uint4*)(pairs + start);
  if (t < 128) cnt[t] = 0;
  __syncthreads();
  for (int i = t; i < nv; i += 256) {
    uint4 v = p4[i];
    atomicAdd(&cnt[v.x & 127u], 1);
    atomicAdd(&cnt[v.y & 127u], 1);
    atomicAdd(&cnt[v.z & 127u], 1);
    atomicAdd(&cnt[v.w & 127u], 1);
  }
  for (int i = (nv << 2) + t; i < cntb; i += 256)
    atomicAdd(&cnt[pairs[start + i] & 127u], 1);
  __syncthreads();
  if (t < 128) exc[t] = cnt[t];
  __syncthreads();
  for (int s = 1; s < 128; s <<= 1) {
    int add = 0;
    if (t < 128 && t >= s) add = exc[t - s];
    __syncthreads();
    if (t < 128) exc[t] += add;
    __syncthreads();
  }
  if (t < 128) {
    int e = exc[t] - cnt[t];
    cur[t] = e;
    int nd = n0 + t;
    if (nd < NN) {
      row_start[nd] = start + e;
      deg[nd] = cnt[t];
    }
  }
  __syncthreads();
  for (int i = t; i < nv; i += 256) {
    uint4 v = p4[i];
#pragma unroll
    for (int e = 0; e < 4; ++e) {
      unsigned pk = (&v.x)[e];
      int pos = atomicAdd(&cur[pk & 127u], 1);
      if (pos < CAPB) buf[pos] = (int)(pk >> 7);
    }
  }
  for (int i = (nv << 2) + t; i < cntb; i += 256) {
    unsigned pk = pairs[start + i];
    int pos = atomicAdd(&cur[pk & 127u], 1);
    if (pos < CAPB) buf[pos] = (int)(pk >> 7);
  }
  __syncthreads();
  int4* o4 = (int4*)(sorted_src + start);
  const int4* b4 = (const int4*)buf;
  for (int i = t; i < nv; i += 256) o4[i] = b4[i];
  for (int i = (nv << 2) + t; i < cntb; i += 256)
    sorted_src[start + i] = buf[i];
}

// ---------------- gemm core (xT already staged in LDS) ------------------------------

__device__ __forceinline__ void gemm_core(int n0, const float* __restrict__ a_src,
                                          const float* __restrict__ a_dst,
                                          __half* __restrict__ h16,
                                          float* __restrict__ s_src,
                                          float* __restrict__ s_dst, char* arena) {
  float* wlds = (float*)arena;
  float (*xT)[68] = (float (*)[68])(arena + 16384);
  float (*psrc)[17] = (float (*)[17])(arena + 16384 + 17408);
  float (*pdst)[17] = (float (*)[17])(arena + 16384 + 17408 + 4352);
  int t = threadIdx.x;
  int tr = t & 15, tc = t >> 4;
  float acc[4][4] = {};
#pragma unroll 8
  for (int k = 0; k < 64; ++k) {
    float4 xa = *(const float4*)&xT[k][tr * 4];
    float4 wv = *(const float4*)&wlds[k * 64 + tc * 4];
    float xs[4] = {xa.x, xa.y, xa.z, xa.w};
    float wj[4] = {wv.x, wv.y, wv.z, wv.w};
#pragma unroll
    for (int i = 0; i < 4; ++i)
#pragma unroll
      for (int j = 0; j < 4; ++j) acc[i][j] = fmaf(xs[i], wj[j], acc[i][j]);
  }
#pragma unroll
  for (int i = 0; i < 4; ++i) {
    int n = n0 + tr * 4 + i;
    if (n < NN) {
      __half2* dst = (__half2*)&h16[(size_t)n * 64 + tc * 4];
      dst[0] = __floats2half2_rn(acc[i][0], acc[i][1]);
      dst[1] = __floats2half2_rn(acc[i][2], acc[i][3]);
    }
  }
  float as[4], ad[4];
#pragma unroll
  for (int j = 0; j < 4; ++j) { as[j] = a_src[tc * 4 + j]; ad[j] = a_dst[tc * 4 + j]; }
#pragma unroll
  for (int i = 0; i < 4; ++i) {
    float p1 = 0.f, p2 = 0.f;
#pragma unroll
    for (int j = 0; j < 4; ++j) { p1 = fmaf(acc[i][j], as[j], p1); p2 = fmaf(acc[i][j], ad[j], p2); }
    psrc[tr * 4 + i][tc] = p1;
    pdst[tr * 4 + i][tc] = p2;
  }
  __syncthreads();
  if (t < 64) {
    int n = n0 + t;
    if (n < NN) {
      float s1 = 0.f, s2 = 0.f;
#pragma unroll
      for (int c = 0; c < 16; ++c) { s1 += psrc[t][c]; s2 += pdst[t][c]; }
      s_src[n] = s1;
      s_dst[n] = s2;
    }
  }
}

// gemm from global input (layer 1): stage x into xT, then core.
__device__ __forceinline__ void gemm_body(int gblk, const float* __restrict__ xin,
                                          const float* __restrict__ W,
                                          const float* __restrict__ a_src,
                                          const float* __restrict__ a_dst,
                                          __half* __restrict__ h16,
                                          float* __restrict__ s_src,
                                          float* __restrict__ s_dst, char* arena) {
  float* wlds = (float*)arena;
  float (*xT)[68] = (float (*)[68])(arena + 16384);
  int t = threadIdx.x;
  int n0 = gblk * 64;
  const float4* W4 = (const float4*)W;
  float4* wl4 = (float4*)wlds;
#pragma unroll
  for (int i = 0; i < 4; ++i) wl4[t + 256 * i] = W4[t + 256 * i];
#pragma unroll
  for (int i = 0; i < 4; ++i) {
    int idx = t + 256 * i;
    int r = idx >> 4, c4 = idx & 15;
    int n = n0 + r;
    float4 v = make_float4(0.f, 0.f, 0.f, 0.f);
    if (n < NN) v = ((const float4*)xin)[(size_t)n * 16 + c4];
    xT[c4 * 4 + 0][r] = v.x;
    xT[c4 * 4 + 1][r] = v.y;
    xT[c4 * 4 + 2][r] = v.z;
    xT[c4 * 4 + 3][r] = v.w;
  }
  __syncthreads();
  gemm_core(n0, a_src, a_dst, h16, s_src, s_dst, arena);
}

// ---------------- kernels --------------------------------------------------

__global__ __launch_bounds__(256) void bin_gemm1(
    const int* __restrict__ ei, int* __restrict__ gcur, unsigned* __restrict__ pairs,
    const float* __restrict__ xin, const float* __restrict__ W,
    const float* __restrict__ a_src, const float* __restrict__ a_dst,
    __half* __restrict__ h16, float* __restrict__ s_src, float* __restrict__ s_dst) {
  __shared__ __align__(16) char arena[ARENA_BYTES];
  if (blockIdx.x < EBLKS) {
    bin_body(blockIdx.x, ei, gcur, pairs, arena);
  } else {
    gemm_body(blockIdx.x - EBLKS, xin, W, a_src, a_dst, h16, s_src, s_dst, arena);
  }
}

__global__ __launch_bounds__(256) void sort_gemm1(
    const unsigned* __restrict__ pairs, const int* __restrict__ gcur,
    int* __restrict__ row_start, int* __restrict__ deg, int* __restrict__ sorted_src,
    const float* __restrict__ xin, const float* __restrict__ W,
    const float* __restrict__ a_src, const float* __restrict__ a_dst,
    __half* __restrict__ h16, float* __restrict__ s_src, float* __restrict__ s_dst) {
  __shared__ __align__(16) char arena[ARENA_BYTES];
  if (blockIdx.x < NBUCK) {
    sort_body(blockIdx.x, pairs, gcur, row_start, deg, sorted_src, arena);
  } else {
    gemm_body(blockIdx.x - NBUCK + GH, xin, W, a_src, a_dst, h16, s_src, s_dst, arena);
  }
}

// FUSED layer boundary: block = 64-node tile. Phase 1: 8 groups of 32 lanes each
// aggregate 8 nodes serially (R10-proven inner loop), apply bias+relu, write fp32
// results straight into the xT LDS tile. Phase 2: proven gemm core for next layer.
// No global barrier needed: gemm tile consumes only its own nodes' agg outputs;
// h16/s double-buffer a<->b so gather table != write table.
__global__ __launch_bounds__(256) void agg_gemm(
    const int* __restrict__ sorted_src, const int* __restrict__ row_start,
    const int* __restrict__ deg, const float* __restrict__ ss_in,
    const float* __restrict__ sd_in, const __half* __restrict__ h_in,
    const float* __restrict__ bias,
    const float* __restrict__ W, const float* __restrict__ a_src,
    const float* __restrict__ a_dst, __half* __restrict__ h_out,
    float* __restrict__ ss_out, float* __restrict__ sd_out) {
  __shared__ __align__(16) char arena[ARENA_BYTES];
  float* wlds = (float*)arena;
  float (*xT)[68] = (float (*)[68])(arena + 16384);
  int t = threadIdx.x;
  int n0 = blockIdx.x * 64;
  // stage W early (completes before the post-agg __syncthreads)
  const float4* W4 = (const float4*)W;
  float4* wl4 = (float4*)wlds;
#pragma unroll
  for (int i = 0; i < 4; ++i) wl4[t + 256 * i] = W4[t + 256 * i];

  int g = t >> 5, lane = t & 31;
  float2 bv = *(const float2*)&bias[2 * lane];
  for (int i = 0; i < 8; ++i) {
    int n = n0 + g * 8 + i;
    float ox = 0.f, oy = 0.f;
    if (n < NN) {
      int start = row_start[n];
      int dg = deg[n];
      float sdn = sd_in[n];
      float sself = lrelu(ss_in[n] + sdn);
      float exself = __expf(sself - 8.0f);
      float2 f0 = __half22float2(*(const __half2*)&h_in[(size_t)n * 64 + 2 * lane]);
      float accx = exself * f0.x, accy = exself * f0.y;
      float dpart = 0.0f;
      for (int base = 0; base < dg; base += 32) {
        int ii = base + lane;
        bool act = (ii < dg);
        int msrc = act ? __builtin_nontemporal_load(&sorted_src[start + ii]) : 0;
        float s = act ? lrelu(ss_in[msrc] + sdn) : -INFINITY;
        float ex = __expf(s - 8.0f);
        dpart += ex;
        unsigned pk = ((unsigned)msrc << 16) |
                      (unsigned)__half_as_ushort(__float2half_rn(ex));
        int nch = (dg - base < 32) ? (dg - base) : 32;
        for (int b0 = 0; b0 < nch; b0 += 8) {
          unsigned pu[8]; unsigned vv[8];
#pragma unroll
          for (int e = 0; e < 8; ++e)
            pu[e] = __shfl(pk, b0 + e, 32);
#pragma unroll
          for (int e = 0; e < 8; ++e)
            vv[e] = *(const unsigned*)&h_in[(size_t)(pu[e] >> 16) * 64 + 2 * lane];
#pragma unroll
          for (int e = 0; e < 8; ++e) {
            float xf = __half2float(__ushort_as_half((unsigned short)(pu[e] & 0xFFFFu)));
            float2 f = __half22float2(*(__half2*)&vv[e]);
            accx = fmaf(xf, f.x, accx);
            accy = fmaf(xf, f.y, accy);
          }
        }
      }
#pragma unroll
      for (int off = 16; off > 0; off >>= 1)
        dpart += __shfl_xor(dpart, off, 32);
      float d = exself + dpart;
      ox = fmaxf(accx / d + bv.x, 0.f);   // bias + relu (next layer's input)
      oy = fmaxf(accy / d + bv.y, 0.f);
    }
    int nloc = g * 8 + i;
    xT[2 * lane][nloc] = ox;
    xT[2 * lane + 1][nloc] = oy;
  }
  __syncthreads();
  gemm_core(n0, a_src, a_dst, h_out, ss_out, sd_out, arena);
}

// Final-layer aggregation (R10-proven): writes fp32 out + bias, no relu.
__global__ void agg_kernel(const int* __restrict__ sorted_src, const int* __restrict__ row_start,
                           const int* __restrict__ deg, const float* __restrict__ s_src,
                           const float* __restrict__ s_dst, const __half* __restrict__ h16,
                           const float* __restrict__ bias, float* __restrict__ out) {
  int gid = blockIdx.x * blockDim.x + threadIdx.x;
  int n = gid >> 5;
  if (n >= NN) return;
  int lane = threadIdx.x & 31;
  int start = row_start[n];
  int dg = deg[n];
  float sdn = s_dst[n];
  float sself = lrelu(s_src[n] + sdn);
  float exself = __expf(sself - 8.0f);
  float2 acc;
  {
    float2 f = __half22float2(*(const __half2*)&h16[(size_t)n * 64 + 2 * lane]);
    acc.x = exself * f.x;
    acc.y = exself * f.y;
  }
  float dpart = 0.0f;
  for (int base = 0; base < dg; base += 32) {
    int i = base + lane;
    bool act = (i < dg);
    int msrc = act ? __builtin_nontemporal_load(&sorted_src[start + i]) : 0;
    float s = act ? lrelu(s_src[msrc] + sdn) : -INFINITY;
    float ex = __expf(s - 8.0f);
    dpart += ex;
    unsigned pk = ((unsigned)msrc << 16) |
                  (unsigned)__half_as_ushort(__float2half_rn(ex));
    int nch = (dg - base < 32) ? (dg - base) : 32;
    for (int b0 = 0; b0 < nch; b0 += 8) {
      unsigned pu[8]; unsigned vv[8];
#pragma unroll
      for (int e = 0; e < 8; ++e)
        pu[e] = __shfl(pk, b0 + e, 32);
#pragma unroll
      for (int e = 0; e < 8; ++e)
        vv[e] = *(const unsigned*)&h16[(size_t)(pu[e] >> 16) * 64 + 2 * lane];
#pragma unroll
      for (int e = 0; e < 8; ++e) {
        float xf = __half2float(__ushort_as_half((unsigned short)(pu[e] & 0xFFFFu)));
        float2 f = __half22float2(*(__half2*)&vv[e]);
        acc.x = fmaf(xf, f.x, acc.x);
        acc.y = fmaf(xf, f.y, acc.y);
      }
    }
  }
#pragma unroll
  for (int off = 16; off > 0; off >>= 1)
    dpart += __shfl_xor(dpart, off, 32);
  float d = exself + dpart;
  float2 bv = *(const float2*)&bias[2 * lane];
  float2 o;
  o.x = acc.x / d + bv.x;
  o.y = acc.y / d + bv.y;
  *(float2*)&out[(size_t)n * 64 + 2 * lane] = o;
}

// ---------------- host-side orchestration --------------------------------------------

extern "C" void kernel_launch(void* const* d_in, const int* in_sizes, int n_in,
                              void* d_out, int out_size, void* d_ws, size_t ws_size,
                              hipStream_t stream) {
  const float* x  = (const float*)d_in[1];
  const int*   ei = (const int*)d_in[2];
  const float* W1 = (const float*)d_in[3];
  const float* as1 = (const float*)d_in[4];
  const float* ad1 = (const float*)d_in[5];
  const float* b1 = (const float*)d_in[6];
  const float* W2 = (const float*)d_in[7];
  const float* as2 = (const float*)d_in[8];
  const float* ad2 = (const float*)d_in[9];
  const float* b2 = (const float*)d_in[10];
  const float* W3 = (const float*)d_in[11];
  const float* as3 = (const float*)d_in[12];
  const float* ad3 = (const float*)d_in[13];
  const float* b3 = (const float*)d_in[14];
  float* out = (float*)d_out;

  const size_t ND = (size_t)NN * D;
  char* base = (char*)d_ws;
  __half* h_a    = (__half*)base;                    // ND halves = 6.4 MB
  __half* h_b    = (__half*)(base + ND * 2);         // ND halves = 6.4 MB
  float* ss_a    = (float*)(base + ND * 4);          // NN
  float* sd_a    = ss_a + NN;                        // NN
  float* ss_b    = sd_a + NN;                        // NN
  float* sd_b    = ss_b + NN;                        // NN
  int* row_start = (int*)(sd_b + NN);                // NN
  int* deg       = row_start + NN;                   // NN
  int* gcur      = deg + NN;                         // NBUCK
  int* sorted_src= gcur + NBUCK;                     // NBUCK*CAPB = 6.4 MB
  // pairs aliases h_b: pairs dead after sort_gemm1; h_b first written by agg_gemm #1.
  unsigned* pairs = (unsigned*)h_b;                  // NBUCK*CAPB u32 = 6.4 MB

  const int AGG_BLOCKS = (NN * 32 + 255) / 256;

  // ---- CSR build overlapped with layer-1 GEMM (split across both launches) ----
  hipMemsetAsync(gcur, 0, (size_t)NBUCK * sizeof(int), stream);
  bin_gemm1<<<EBLKS + GH, 256, 0, stream>>>(ei, gcur, pairs, x, W1, as1, ad1,
                                            h_a, ss_a, sd_a);
  sort_gemm1<<<NBUCK + (GB - GH), 256, 0, stream>>>(pairs, gcur, row_start, deg, sorted_src,
                                                    x, W1, as1, ad1, h_a, ss_a, sd_a);

  // ---- fused layer boundaries: agg(L) + gemm(L+1) ----
  agg_gemm<<<GB, 256, 0, stream>>>(sorted_src, row_start, deg, ss_a, sd_a, h_a, b1,
                                   W2, as2, ad2, h_b, ss_b, sd_b);
  agg_gemm<<<GB, 256, 0, stream>>>(sorted_src, row_start, deg, ss_b, sd_b, h_b, b2,
                                   W3, as3, ad3, h_a, ss_a, sd_a);

  // ---- final aggregation ----
  agg_kernel<<<AGG_BLOCKS, 256, 0, stream>>>(sorted_src, row_start, deg, ss_a, sd_a,
                                             h_a, b3, out);
}

// Round 14
// 161.244 us; speedup vs baseline: 1.1483x; 1.1483x over previous
//
#include <hip/hip_runtime.h>
#include <hip/hip_fp16.h>

#define NN 50000
#define NE 800000
#define D 64
#define GB ((NN + 63) / 64)       // 782 gemm blocks
#define GH 391                    // gemm1 split: half with bin, half with sort
#define NBUCK ((NN + 127) >> 7)   // 391 buckets of 128 dst nodes
#define CHUNK 4096
#define EBLKS ((NE + CHUNK - 1) / CHUNK)   // 196 bin blocks
#define CAPB 4096                 // per-bucket capacity (mean 2046, sd 45 -> +45 sigma)
#define ARENA_BYTES (16384 + 17408 + 4352 + 4352)

__device__ __forceinline__ float lrelu(float s) { return (s > 0.0f) ? s : 0.2f * s; }

// ---------------- CSR bodies --------------------------------------------------

__device__ __forceinline__ void bin_body(int blk, const int* __restrict__ ei,
                                         int* __restrict__ gcur,
                                         unsigned* __restrict__ pairs, char* arena) {
  int* cnt_loc = (int*)arena;            // NBUCK
  int* base_loc = cnt_loc + NBUCK;       // NBUCK
  int t = threadIdx.x;
  int e0 = blk * CHUNK;
  int n = (NE - e0 < CHUNK) ? (NE - e0) : CHUNK;
  int nv = n >> 2;
  const int4* d4 = (const int4*)(ei + NE + e0);
  const int4* s4 = (const int4*)(ei + e0);
  for (int i = t; i < NBUCK; i += 256) cnt_loc[i] = 0;
  __syncthreads();
  for (int i = t; i < nv; i += 256) {
    int4 v = d4[i];
    atomicAdd(&cnt_loc[v.x >> 7], 1);
    atomicAdd(&cnt_loc[v.y >> 7], 1);
    atomicAdd(&cnt_loc[v.z >> 7], 1);
    atomicAdd(&cnt_loc[v.w >> 7], 1);
  }
  __syncthreads();
  for (int i = t; i < NBUCK; i += 256) {
    int c = cnt_loc[i];
    base_loc[i] = c ? (i * CAPB + atomicAdd(&gcur[i], c)) : 0;
    cnt_loc[i] = 0;
  }
  __syncthreads();
  for (int i = t; i < nv; i += 256) {
    int4 sv = s4[i];
    int4 dv = d4[i];
#pragma unroll
    for (int e = 0; e < 4; ++e) {
      int src = (&sv.x)[e];
      int dst = (&dv.x)[e];
      int b = dst >> 7;
      int off = atomicAdd(&cnt_loc[b], 1);
      unsigned pk = ((unsigned)src << 7) | (unsigned)(dst & 127);
      __builtin_nontemporal_store(pk, &pairs[base_loc[b] + off]);
    }
  }
}

// Per-bucket exact sort + degree-paired node permutation (counting sort by degree).
__device__ __forceinline__ void sort_body(int b, const unsigned* __restrict__ pairs,
                                          const int* __restrict__ gcur,
                                          int* __restrict__ row_start,
                                          int* __restrict__ deg,
                                          int* __restrict__ sorted_src,
                                          int* __restrict__ perm, char* arena) {
  int* cnt = (int*)arena;        // 128
  int* exc = cnt + 128;          // 128
  int* cur = exc + 128;          // 128
  int* buf = cur + 128;          // CAPB
  int* dcnt = buf + CAPB;        // 64
  int* dexc = dcnt + 64;         // 64
  int t = threadIdx.x;
  int n0 = b << 7;
  int start = b * CAPB;
  int cntb = gcur[b];
  if (cntb > CAPB) cntb = CAPB;
  int nv = cntb >> 2;
  const uint4* p4 = (const uint4*)(pairs + start);
  if (t < 128) cnt[t] = 0;
  __syncthreads();
  for (int i = t; i < nv; i += 256) {
    uint4 v = p4[i];
    atomicAdd(&cnt[v.x & 127u], 1);
    atomicAdd(&cnt[v.y & 127u], 1);
    atomicAdd(&cnt[v.z & 127u], 1);
    atomicAdd(&cnt[v.w & 127u], 1);
  }
  for (int i = (nv << 2) + t; i < cntb; i += 256)
    atomicAdd(&cnt[pairs[start + i] & 127u], 1);
  __syncthreads();
  if (t < 128) exc[t] = cnt[t];
  __syncthreads();
  for (int s = 1; s < 128; s <<= 1) {
    int add = 0;
    if (t < 128 && t >= s) add = exc[t - s];
    __syncthreads();
    if (t < 128) exc[t] += add;
    __syncthreads();
  }
  if (t < 128) {
    int e = exc[t] - cnt[t];
    cur[t] = e;
    int nd = n0 + t;
    if (nd < NN) {
      row_start[nd] = start + e;
      deg[nd] = cnt[t];
    }
  }
  __syncthreads();
  for (int i = t; i < nv; i += 256) {
    uint4 v = p4[i];
#pragma unroll
    for (int e = 0; e < 4; ++e) {
      unsigned pk = (&v.x)[e];
      int pos = atomicAdd(&cur[pk & 127u], 1);
      if (pos < CAPB) buf[pos] = (int)(pk >> 7);
    }
  }
  for (int i = (nv << 2) + t; i < cntb; i += 256) {
    unsigned pk = pairs[start + i];
    int pos = atomicAdd(&cur[pk & 127u], 1);
    if (pos < CAPB) buf[pos] = (int)(pk >> 7);
  }
  __syncthreads();
  int4* o4 = (int4*)(sorted_src + start);
  const int4* b4 = (const int4*)buf;
  for (int i = t; i < nv; i += 256) o4[i] = b4[i];
  for (int i = (nv << 2) + t; i < cntb; i += 256)
    sorted_src[start + i] = buf[i];

  // ---- degree-paired permutation: counting-sort bucket's nodes by degree ----
  int nvalid = (NN - n0 < 128) ? (NN - n0) : 128;
  if (t < 64) dcnt[t] = 0;
  __syncthreads();
  int myd = 0;
  if (t < nvalid) {
    myd = cnt[t];
    if (myd > 63) myd = 63;
    atomicAdd(&dcnt[myd], 1);
  }
  __syncthreads();
  if (t < 64) dexc[t] = dcnt[t];
  __syncthreads();
  for (int s = 1; s < 64; s <<= 1) {
    int add = 0;
    if (t < 64 && t >= s) add = dexc[t - s];
    __syncthreads();
    if (t < 64) dexc[t] += add;
    __syncthreads();
  }
  if (t < 64) dcnt[t] = dexc[t] - dcnt[t];   // exclusive start per degree value
  __syncthreads();
  if (t < nvalid) {
    int r = atomicAdd(&dcnt[myd], 1);
    perm[n0 + r] = n0 + t;
  }
}

// ---------------- gemm body --------------------------------------------------

__device__ __forceinline__ void gemm_body(int gblk, const float* __restrict__ xin,
                                          const float* __restrict__ W,
                                          const float* __restrict__ a_src,
                                          const float* __restrict__ a_dst,
                                          __half* __restrict__ h16,
                                          float* __restrict__ s_src,
                                          float* __restrict__ s_dst, int do_relu,
                                          char* arena) {
  float* wlds = (float*)arena;                              // 64*64
  float (*xT)[68] = (float (*)[68])(arena + 16384);         // 64x68
  float (*psrc)[17] = (float (*)[17])(arena + 16384 + 17408);
  float (*pdst)[17] = (float (*)[17])(arena + 16384 + 17408 + 4352);
  int t = threadIdx.x;
  int n0 = gblk * 64;

  const float4* W4 = (const float4*)W;
  float4* wl4 = (float4*)wlds;
#pragma unroll
  for (int i = 0; i < 4; ++i) wl4[t + 256 * i] = W4[t + 256 * i];

#pragma unroll
  for (int i = 0; i < 4; ++i) {
    int idx = t + 256 * i;
    int r = idx >> 4, c4 = idx & 15;
    int n = n0 + r;
    float4 v = make_float4(0.f, 0.f, 0.f, 0.f);
    if (n < NN) v = ((const float4*)xin)[(size_t)n * 16 + c4];
    if (do_relu) {
      v.x = fmaxf(v.x, 0.f); v.y = fmaxf(v.y, 0.f);
      v.z = fmaxf(v.z, 0.f); v.w = fmaxf(v.w, 0.f);
    }
    xT[c4 * 4 + 0][r] = v.x;
    xT[c4 * 4 + 1][r] = v.y;
    xT[c4 * 4 + 2][r] = v.z;
    xT[c4 * 4 + 3][r] = v.w;
  }
  __syncthreads();

  int tr = t & 15, tc = t >> 4;   // nodes tr*4..+3, cols tc*4..+3
  float acc[4][4] = {};
#pragma unroll 8
  for (int k = 0; k < 64; ++k) {
    float4 xa = *(const float4*)&xT[k][tr * 4];
    float4 wv = *(const float4*)&wlds[k * 64 + tc * 4];
    float xs[4] = {xa.x, xa.y, xa.z, xa.w};
    float wj[4] = {wv.x, wv.y, wv.z, wv.w};
#pragma unroll
    for (int i = 0; i < 4; ++i)
#pragma unroll
      for (int j = 0; j < 4; ++j) acc[i][j] = fmaf(xs[i], wj[j], acc[i][j]);
  }

#pragma unroll
  for (int i = 0; i < 4; ++i) {
    int n = n0 + tr * 4 + i;
    if (n < NN) {
      __half2* dst = (__half2*)&h16[(size_t)n * 64 + tc * 4];
      dst[0] = __floats2half2_rn(acc[i][0], acc[i][1]);
      dst[1] = __floats2half2_rn(acc[i][2], acc[i][3]);
    }
  }

  float as[4], ad[4];
#pragma unroll
  for (int j = 0; j < 4; ++j) { as[j] = a_src[tc * 4 + j]; ad[j] = a_dst[tc * 4 + j]; }
#pragma unroll
  for (int i = 0; i < 4; ++i) {
    float p1 = 0.f, p2 = 0.f;
#pragma unroll
    for (int j = 0; j < 4; ++j) { p1 = fmaf(acc[i][j], as[j], p1); p2 = fmaf(acc[i][j], ad[j], p2); }
    psrc[tr * 4 + i][tc] = p1;
    pdst[tr * 4 + i][tc] = p2;
  }
  __syncthreads();
  if (t < 64) {
    int n = n0 + t;
    if (n < NN) {
      float s1 = 0.f, s2 = 0.f;
#pragma unroll
      for (int c = 0; c < 16; ++c) { s1 += psrc[t][c]; s2 += pdst[t][c]; }
      s_src[n] = s1;
      s_dst[n] = s2;
    }
  }
}

// ---------------- kernels --------------------------------------------------

__global__ __launch_bounds__(256) void bin_gemm1(
    const int* __restrict__ ei, int* __restrict__ gcur, unsigned* __restrict__ pairs,
    const float* __restrict__ xin, const float* __restrict__ W,
    const float* __restrict__ a_src, const float* __restrict__ a_dst,
    __half* __restrict__ h16, float* __restrict__ s_src, float* __restrict__ s_dst) {
  __shared__ __align__(16) char arena[ARENA_BYTES];
  if (blockIdx.x < EBLKS) {
    bin_body(blockIdx.x, ei, gcur, pairs, arena);
  } else {
    gemm_body(blockIdx.x - EBLKS, xin, W, a_src, a_dst, h16, s_src, s_dst, 0, arena);
  }
}

__global__ __launch_bounds__(256) void sort_gemm1(
    const unsigned* __restrict__ pairs, const int* __restrict__ gcur,
    int* __restrict__ row_start, int* __restrict__ deg, int* __restrict__ sorted_src,
    int* __restrict__ perm,
    const float* __restrict__ xin, const float* __restrict__ W,
    const float* __restrict__ a_src, const float* __restrict__ a_dst,
    __half* __restrict__ h16, float* __restrict__ s_src, float* __restrict__ s_dst) {
  __shared__ __align__(16) char arena[ARENA_BYTES];
  if (blockIdx.x < NBUCK) {
    sort_body(blockIdx.x, pairs, gcur, row_start, deg, sorted_src, perm, arena);
  } else {
    gemm_body(blockIdx.x - NBUCK + GH, xin, W, a_src, a_dst, h16, s_src, s_dst, 0, arena);
  }
}

// Standalone GEMM for layers 2-3.
__global__ __launch_bounds__(256) void gemm_feat(
    const float* __restrict__ xin, const float* __restrict__ W,
    const float* __restrict__ a_src, const float* __restrict__ a_dst,
    __half* __restrict__ h16, float* __restrict__ s_src, float* __restrict__ s_dst,
    int do_relu) {
  __shared__ __align__(16) char arena[ARENA_BYTES];
  gemm_body(blockIdx.x, xin, W, a_src, a_dst, h16, s_src, s_dst, do_relu, arena);
}

// R12-proven agg + degree-paired scheduling: wave-mates get equal-degree nodes via
// perm, eliminating ~11% padded-slot waste from E[max(deg_a,deg_b)] > E[deg].
__global__ void agg_kernel(const int* __restrict__ sorted_src, const int* __restrict__ row_start,
                           const int* __restrict__ deg, const int* __restrict__ perm,
                           const float* __restrict__ s_src,
                           const float* __restrict__ s_dst, const __half* __restrict__ h16,
                           const float* __restrict__ bias, float* __restrict__ out) {
  int gid = blockIdx.x * blockDim.x + threadIdx.x;
  int slot = gid >> 5;
  if (slot >= NN) return;
  int n = perm[slot];
  int lane = threadIdx.x & 31;   // lane within the 32-lane group
  int start = row_start[n];
  int dg = deg[n];
  float sdn = s_dst[n];
  float sself = lrelu(s_src[n] + sdn);
  float exself = __expf(sself - 8.0f);

  float2 acc;
  {
    float2 f = __half22float2(*(const __half2*)&h16[(size_t)n * 64 + 2 * lane]);
    acc.x = exself * f.x;
    acc.y = exself * f.y;
  }
  float dpart = 0.0f;
  for (int base = 0; base < dg; base += 32) {
    int i = base + lane;
    bool act = (i < dg);
    int msrc = act ? __builtin_nontemporal_load(&sorted_src[start + i]) : 0;
    float s = act ? lrelu(s_src[msrc] + sdn) : -INFINITY;
    float ex = __expf(s - 8.0f);   // 0 for inactive lanes
    dpart += ex;
    unsigned pk = ((unsigned)msrc << 16) |
                  (unsigned)__half_as_ushort(__float2half_rn(ex));
    int nch = (dg - base < 32) ? (dg - base) : 32;
    for (int b0 = 0; b0 < nch; b0 += 8) {
      unsigned pu[8]; unsigned vv[8];
#pragma unroll
      for (int e = 0; e < 8; ++e)
        pu[e] = __shfl(pk, b0 + e, 32);
#pragma unroll
      for (int e = 0; e < 8; ++e)
        vv[e] = *(const unsigned*)&h16[(size_t)(pu[e] >> 16) * 64 + 2 * lane];
#pragma unroll
      for (int e = 0; e < 8; ++e) {
        float xf = __half2float(__ushort_as_half((unsigned short)(pu[e] & 0xFFFFu)));
        float2 f = __half22float2(*(__half2*)&vv[e]);
        acc.x = fmaf(xf, f.x, acc.x);
        acc.y = fmaf(xf, f.y, acc.y);
      }
    }
  }
#pragma unroll
  for (int off = 16; off > 0; off >>= 1)
    dpart += __shfl_xor(dpart, off, 32);
  float d = exself + dpart;
  float2 bv = *(const float2*)&bias[2 * lane];
  float2 o;
  o.x = acc.x / d + bv.x;
  o.y = acc.y / d + bv.y;
  *(float2*)&out[(size_t)n * 64 + 2 * lane] = o;
}

// ---------------- host-side orchestration --------------------------------------------

extern "C" void kernel_launch(void* const* d_in, const int* in_sizes, int n_in,
                              void* d_out, int out_size, void* d_ws, size_t ws_size,
                              hipStream_t stream) {
  const float* x  = (const float*)d_in[1];
  const int*   ei = (const int*)d_in[2];
  const float* W1 = (const float*)d_in[3];
  const float* as1 = (const float*)d_in[4];
  const float* ad1 = (const float*)d_in[5];
  const float* b1 = (const float*)d_in[6];
  const float* W2 = (const float*)d_in[7];
  const float* as2 = (const float*)d_in[8];
  const float* ad2 = (const float*)d_in[9];
  const float* b2 = (const float*)d_in[10];
  const float* W3 = (const float*)d_in[11];
  const float* as3 = (const float*)d_in[12];
  const float* ad3 = (const float*)d_in[13];
  const float* b3 = (const float*)d_in[14];
  float* out = (float*)d_out;

  const size_t ND = (size_t)NN * D;
  char* base = (char*)d_ws;
  __half* h16    = (__half*)base;                    // ND halves = 6.4 MB
  float* A       = (float*)(base + ND * 2);          // ND floats (12.8 MB)
  float* B       = A + ND;                           // ND floats
  float* s_src   = B + ND;                           // NN
  float* s_dst   = s_src + NN;                       // NN
  int* row_start = (int*)(s_dst + NN);               // NN
  int* deg       = row_start + NN;                   // NN
  int* perm      = deg + NN;                         // NN
  int* gcur      = perm + NN;                        // NBUCK
  int* sorted_src= gcur + NBUCK;                     // NBUCK*CAPB = 6.4 MB
  // pairs aliases A: only live during CSR build, before agg1 writes A.
  unsigned* pairs = (unsigned*)A;                    // NBUCK*CAPB u32 = 6.4 MB (A is 12.8 MB)

  const int AGG_BLOCKS = (NN * 32 + 255) / 256;

  // ---- CSR build overlapped with layer-1 GEMM (split across both launches) ----
  hipMemsetAsync(gcur, 0, (size_t)NBUCK * sizeof(int), stream);
  bin_gemm1<<<EBLKS + GH, 256, 0, stream>>>(ei, gcur, pairs, x, W1, as1, ad1,
                                            h16, s_src, s_dst);
  sort_gemm1<<<NBUCK + (GB - GH), 256, 0, stream>>>(pairs, gcur, row_start, deg, sorted_src,
                                                    perm, x, W1, as1, ad1, h16, s_src, s_dst);

  // ---- layer 1 aggregate ----
  agg_kernel<<<AGG_BLOCKS, 256, 0, stream>>>(sorted_src, row_start, deg, perm, s_src, s_dst,
                                             h16, b1, A);
  // ---- layer 2 ----
  gemm_feat<<<GB, 256, 0, stream>>>(A, W2, as2, ad2, h16, s_src, s_dst, 1);
  agg_kernel<<<AGG_BLOCKS, 256, 0, stream>>>(sorted_src, row_start, deg, perm, s_src, s_dst,
                                             h16, b2, B);
  // ---- layer 3 ----
  gemm_feat<<<GB, 256, 0, stream>>>(B, W3, as3, ad3, h16, s_src, s_dst, 1);
  agg_kernel<<<AGG_BLOCKS, 256, 0, stream>>>(sorted_src, row_start, deg, perm, s_src, s_dst,
                                             h16, b3, out);
}

// Round 15
// 147.645 us; speedup vs baseline: 1.2541x; 1.0921x over previous
//
#include <hip/hip_runtime.h>
#include <hip/hip_fp16.h>

#define NN 50000
#define NE 800000
#define D 64
#define GB ((NN + 63) / 64)       // 782 gemm blocks
#define GH 391                    // gemm1 split: half with bin, half with sort
#define NBUCK ((NN + 127) >> 7)   // 391 buckets of 128 dst nodes
#define CHUNK 4096
#define EBLKS ((NE + CHUNK - 1) / CHUNK)   // 196 bin blocks
#define CAPB 4096                 // per-bucket capacity (mean 2046, sd 45 -> +45 sigma)
#define ARENA_BYTES (16384 + 17408 + 4352 + 4352)

__device__ __forceinline__ float lrelu(float s) { return (s > 0.0f) ? s : 0.2f * s; }

// ---------------- CSR bodies --------------------------------------------------

__device__ __forceinline__ void bin_body(int blk, const int* __restrict__ ei,
                                         int* __restrict__ gcur,
                                         unsigned* __restrict__ pairs, char* arena) {
  int* cnt_loc = (int*)arena;            // NBUCK
  int* base_loc = cnt_loc + NBUCK;       // NBUCK
  int t = threadIdx.x;
  int e0 = blk * CHUNK;
  int n = (NE - e0 < CHUNK) ? (NE - e0) : CHUNK;
  int nv = n >> 2;
  const int4* d4 = (const int4*)(ei + NE + e0);
  const int4* s4 = (const int4*)(ei + e0);
  for (int i = t; i < NBUCK; i += 256) cnt_loc[i] = 0;
  __syncthreads();
  for (int i = t; i < nv; i += 256) {
    int4 v = d4[i];
    atomicAdd(&cnt_loc[v.x >> 7], 1);
    atomicAdd(&cnt_loc[v.y >> 7], 1);
    atomicAdd(&cnt_loc[v.z >> 7], 1);
    atomicAdd(&cnt_loc[v.w >> 7], 1);
  }
  __syncthreads();
  for (int i = t; i < NBUCK; i += 256) {
    int c = cnt_loc[i];
    base_loc[i] = c ? (i * CAPB + atomicAdd(&gcur[i], c)) : 0;
    cnt_loc[i] = 0;
  }
  __syncthreads();
  for (int i = t; i < nv; i += 256) {
    int4 sv = s4[i];
    int4 dv = d4[i];
#pragma unroll
    for (int e = 0; e < 4; ++e) {
      int src = (&sv.x)[e];
      int dst = (&dv.x)[e];
      int b = dst >> 7;
      int off = atomicAdd(&cnt_loc[b], 1);
      unsigned pk = ((unsigned)src << 7) | (unsigned)(dst & 127);
      __builtin_nontemporal_store(pk, &pairs[base_loc[b] + off]);
    }
  }
}

__device__ __forceinline__ void sort_body(int b, const unsigned* __restrict__ pairs,
                                          const int* __restrict__ gcur,
                                          int* __restrict__ row_start,
                                          int* __restrict__ deg,
                                          int* __restrict__ sorted_src, char* arena) {
  int* cnt = (int*)arena;        // 128
  int* exc = cnt + 128;          // 128
  int* cur = exc + 128;          // 128
  int* buf = cur + 128;          // CAPB
  int t = threadIdx.x;
  int n0 = b << 7;
  int start = b * CAPB;
  int cntb = gcur[b];
  if (cntb > CAPB) cntb = CAPB;
  int nv = cntb >> 2;
  const uint4* p4 = (const uint4*)(pairs + start);
  if (t < 128) cnt[t] = 0;
  __syncthreads();
  for (int i = t; i < nv; i += 256) {
    uint4 v = p4[i];
    atomicAdd(&cnt[v.x & 127u], 1);
    atomicAdd(&cnt[v.y & 127u], 1);
    atomicAdd(&cnt[v.z & 127u], 1);
    atomicAdd(&cnt[v.w & 127u], 1);
  }
  for (int i = (nv << 2) + t; i < cntb; i += 256)
    atomicAdd(&cnt[pairs[start + i] & 127u], 1);
  __syncthreads();
  if (t < 128) exc[t] = cnt[t];
  __syncthreads();
  for (int s = 1; s < 128; s <<= 1) {
    int add = 0;
    if (t < 128 && t >= s) add = exc[t - s];
    __syncthreads();
    if (t < 128) exc[t] += add;
    __syncthreads();
  }
  if (t < 128) {
    int e = exc[t] - cnt[t];
    cur[t] = e;
    int nd = n0 + t;
    if (nd < NN) {
      row_start[nd] = start + e;
      deg[nd] = cnt[t];
    }
  }
  __syncthreads();
  for (int i = t; i < nv; i += 256) {
    uint4 v = p4[i];
#pragma unroll
    for (int e = 0; e < 4; ++e) {
      unsigned pk = (&v.x)[e];
      int pos = atomicAdd(&cur[pk & 127u], 1);
      if (pos < CAPB) buf[pos] = (int)(pk >> 7);
    }
  }
  for (int i = (nv << 2) + t; i < cntb; i += 256) {
    unsigned pk = pairs[start + i];
    int pos = atomicAdd(&cur[pk & 127u], 1);
    if (pos < CAPB) buf[pos] = (int)(pk >> 7);
  }
  __syncthreads();
  int4* o4 = (int4*)(sorted_src + start);
  const int4* b4 = (const int4*)buf;
  for (int i = t; i < nv; i += 256) o4[i] = b4[i];
  for (int i = (nv << 2) + t; i < cntb; i += 256)
    sorted_src[start + i] = buf[i];
}

// ---------------- gemm body --------------------------------------------------

__device__ __forceinline__ void gemm_body(int gblk, const float* __restrict__ xin,
                                          const float* __restrict__ W,
                                          const float* __restrict__ a_src,
                                          const float* __restrict__ a_dst,
                                          __half* __restrict__ h16,
                                          float* __restrict__ s_src,
                                          float* __restrict__ s_dst, int do_relu,
                                          char* arena) {
  float* wlds = (float*)arena;                              // 64*64
  float (*xT)[68] = (float (*)[68])(arena + 16384);         // 64x68
  float (*psrc)[17] = (float (*)[17])(arena + 16384 + 17408);
  float (*pdst)[17] = (float (*)[17])(arena + 16384 + 17408 + 4352);
  int t = threadIdx.x;
  int n0 = gblk * 64;

  const float4* W4 = (const float4*)W;
  float4* wl4 = (float4*)wlds;
#pragma unroll
  for (int i = 0; i < 4; ++i) wl4[t + 256 * i] = W4[t + 256 * i];

#pragma unroll
  for (int i = 0; i < 4; ++i) {
    int idx = t + 256 * i;
    int r = idx >> 4, c4 = idx & 15;
    int n = n0 + r;
    float4 v = make_float4(0.f, 0.f, 0.f, 0.f);
    if (n < NN) v = ((const float4*)xin)[(size_t)n * 16 + c4];
    if (do_relu) {
      v.x = fmaxf(v.x, 0.f); v.y = fmaxf(v.y, 0.f);
      v.z = fmaxf(v.z, 0.f); v.w = fmaxf(v.w, 0.f);
    }
    xT[c4 * 4 + 0][r] = v.x;
    xT[c4 * 4 + 1][r] = v.y;
    xT[c4 * 4 + 2][r] = v.z;
    xT[c4 * 4 + 3][r] = v.w;
  }
  __syncthreads();

  int tr = t & 15, tc = t >> 4;   // nodes tr*4..+3, cols tc*4..+3
  float acc[4][4] = {};
#pragma unroll 8
  for (int k = 0; k < 64; ++k) {
    float4 xa = *(const float4*)&xT[k][tr * 4];
    float4 wv = *(const float4*)&wlds[k * 64 + tc * 4];
    float xs[4] = {xa.x, xa.y, xa.z, xa.w};
    float wj[4] = {wv.x, wv.y, wv.z, wv.w};
#pragma unroll
    for (int i = 0; i < 4; ++i)
#pragma unroll
      for (int j = 0; j < 4; ++j) acc[i][j] = fmaf(xs[i], wj[j], acc[i][j]);
  }

#pragma unroll
  for (int i = 0; i < 4; ++i) {
    int n = n0 + tr * 4 + i;
    if (n < NN) {
      __half2* dst = (__half2*)&h16[(size_t)n * 64 + tc * 4];
      dst[0] = __floats2half2_rn(acc[i][0], acc[i][1]);
      dst[1] = __floats2half2_rn(acc[i][2], acc[i][3]);
    }
  }

  float as[4], ad[4];
#pragma unroll
  for (int j = 0; j < 4; ++j) { as[j] = a_src[tc * 4 + j]; ad[j] = a_dst[tc * 4 + j]; }
#pragma unroll
  for (int i = 0; i < 4; ++i) {
    float p1 = 0.f, p2 = 0.f;
#pragma unroll
    for (int j = 0; j < 4; ++j) { p1 = fmaf(acc[i][j], as[j], p1); p2 = fmaf(acc[i][j], ad[j], p2); }
    psrc[tr * 4 + i][tc] = p1;
    pdst[tr * 4 + i][tc] = p2;
  }
  __syncthreads();
  if (t < 64) {
    int n = n0 + t;
    if (n < NN) {
      float s1 = 0.f, s2 = 0.f;
#pragma unroll
      for (int c = 0; c < 16; ++c) { s1 += psrc[t][c]; s2 += pdst[t][c]; }
      s_src[n] = s1;
      s_dst[n] = s2;
    }
  }
}

// ---------------- kernels --------------------------------------------------

__global__ __launch_bounds__(256) void bin_gemm1(
    const int* __restrict__ ei, int* __restrict__ gcur, unsigned* __restrict__ pairs,
    const float* __restrict__ xin, const float* __restrict__ W,
    const float* __restrict__ a_src, const float* __restrict__ a_dst,
    __half* __restrict__ h16, float* __restrict__ s_src, float* __restrict__ s_dst) {
  __shared__ __align__(16) char arena[ARENA_BYTES];
  if (blockIdx.x < EBLKS) {
    bin_body(blockIdx.x, ei, gcur, pairs, arena);
  } else {
    gemm_body(blockIdx.x - EBLKS, xin, W, a_src, a_dst, h16, s_src, s_dst, 0, arena);
  }
}

__global__ __launch_bounds__(256) void sort_gemm1(
    const unsigned* __restrict__ pairs, const int* __restrict__ gcur,
    int* __restrict__ row_start, int* __restrict__ deg, int* __restrict__ sorted_src,
    const float* __restrict__ xin, const float* __restrict__ W,
    const float* __restrict__ a_src, const float* __restrict__ a_dst,
    __half* __restrict__ h16, float* __restrict__ s_src, float* __restrict__ s_dst) {
  __shared__ __align__(16) char arena[ARENA_BYTES];
  if (blockIdx.x < NBUCK) {
    sort_body(blockIdx.x, pairs, gcur, row_start, deg, sorted_src, arena);
  } else {
    gemm_body(blockIdx.x - NBUCK + GH, xin, W, a_src, a_dst, h16, s_src, s_dst, 0, arena);
  }
}

// Standalone GEMM for layers 2-3.
__global__ __launch_bounds__(256) void gemm_feat(
    const float* __restrict__ xin, const float* __restrict__ W,
    const float* __restrict__ a_src, const float* __restrict__ a_dst,
    __half* __restrict__ h16, float* __restrict__ s_src, float* __restrict__ s_dst,
    int do_relu) {
  __shared__ __align__(16) char arena[ARENA_BYTES];
  gemm_body(blockIdx.x, xin, W, a_src, a_dst, h16, s_src, s_dst, do_relu, arena);
}

// R12-proven agg: TWO nodes per wave; 32-lane group per dst node; lane = half2
// feature pair; packed single-shuffle per edge (src<<16 | fp16(ex)); 8-deep batches.
__global__ void agg_kernel(const int* __restrict__ sorted_src, const int* __restrict__ row_start,
                           const int* __restrict__ deg, const float* __restrict__ s_src,
                           const float* __restrict__ s_dst, const __half* __restrict__ h16,
                           const float* __restrict__ bias, float* __restrict__ out) {
  int gid = blockIdx.x * blockDim.x + threadIdx.x;
  int n = gid >> 5;
  if (n >= NN) return;
  int lane = threadIdx.x & 31;   // lane within the 32-lane group
  int start = row_start[n];
  int dg = deg[n];
  float sdn = s_dst[n];
  float sself = lrelu(s_src[n] + sdn);
  float exself = __expf(sself - 8.0f);

  float2 acc;
  {
    float2 f = __half22float2(*(const __half2*)&h16[(size_t)n * 64 + 2 * lane]);
    acc.x = exself * f.x;
    acc.y = exself * f.y;
  }
  float dpart = 0.0f;
  for (int base = 0; base < dg; base += 32) {
    int i = base + lane;
    bool act = (i < dg);
    int msrc = act ? __builtin_nontemporal_load(&sorted_src[start + i]) : 0;
    float s = act ? lrelu(s_src[msrc] + sdn) : -INFINITY;
    float ex = __expf(s - 8.0f);   // 0 for inactive lanes
    dpart += ex;
    unsigned pk = ((unsigned)msrc << 16) |
                  (unsigned)__half_as_ushort(__float2half_rn(ex));
    int nch = (dg - base < 32) ? (dg - base) : 32;
    for (int b0 = 0; b0 < nch; b0 += 8) {
      unsigned pu[8]; unsigned vv[8];
#pragma unroll
      for (int e = 0; e < 8; ++e)
        pu[e] = __shfl(pk, b0 + e, 32);
#pragma unroll
      for (int e = 0; e < 8; ++e)
        vv[e] = *(const unsigned*)&h16[(size_t)(pu[e] >> 16) * 64 + 2 * lane];
#pragma unroll
      for (int e = 0; e < 8; ++e) {
        float xf = __half2float(__ushort_as_half((unsigned short)(pu[e] & 0xFFFFu)));
        float2 f = __half22float2(*(__half2*)&vv[e]);
        acc.x = fmaf(xf, f.x, acc.x);
        acc.y = fmaf(xf, f.y, acc.y);
      }
    }
  }
#pragma unroll
  for (int off = 16; off > 0; off >>= 1)
    dpart += __shfl_xor(dpart, off, 32);
  float d = exself + dpart;
  float2 bv = *(const float2*)&bias[2 * lane];
  float2 o;
  o.x = acc.x / d + bv.x;
  o.y = acc.y / d + bv.y;
  *(float2*)&out[(size_t)n * 64 + 2 * lane] = o;
}

// ---------------- host-side orchestration --------------------------------------------

extern "C" void kernel_launch(void* const* d_in, const int* in_sizes, int n_in,
                              void* d_out, int out_size, void* d_ws, size_t ws_size,
                              hipStream_t stream) {
  const float* x  = (const float*)d_in[1];
  const int*   ei = (const int*)d_in[2];
  const float* W1 = (const float*)d_in[3];
  const float* as1 = (const float*)d_in[4];
  const float* ad1 = (const float*)d_in[5];
  const float* b1 = (const float*)d_in[6];
  const float* W2 = (const float*)d_in[7];
  const float* as2 = (const float*)d_in[8];
  const float* ad2 = (const float*)d_in[9];
  const float* b2 = (const float*)d_in[10];
  const float* W3 = (const float*)d_in[11];
  const float* as3 = (const float*)d_in[12];
  const float* ad3 = (const float*)d_in[13];
  const float* b3 = (const float*)d_in[14];
  float* out = (float*)d_out;

  const size_t ND = (size_t)NN * D;
  char* base = (char*)d_ws;
  __half* h16    = (__half*)base;                    // ND halves = 6.4 MB
  float* A       = (float*)(base + ND * 2);          // ND floats (12.8 MB)
  float* B       = A + ND;                           // ND floats
  float* s_src   = B + ND;                           // NN
  float* s_dst   = s_src + NN;                       // NN
  int* row_start = (int*)(s_dst + NN);               // NN
  int* deg       = row_start + NN;                   // NN
  int* gcur      = deg + NN;                         // NBUCK
  int* sorted_src= gcur + NBUCK;                     // NBUCK*CAPB = 6.4 MB
  // pairs aliases A: only live during CSR build, before agg1 writes A.
  unsigned* pairs = (unsigned*)A;                    // NBUCK*CAPB u32 = 6.4 MB (A is 12.8 MB)

  const int AGG_BLOCKS = (NN * 32 + 255) / 256;

  // ---- CSR build overlapped with layer-1 GEMM (split across both launches) ----
  hipMemsetAsync(gcur, 0, (size_t)NBUCK * sizeof(int), stream);
  bin_gemm1<<<EBLKS + GH, 256, 0, stream>>>(ei, gcur, pairs, x, W1, as1, ad1,
                                            h16, s_src, s_dst);
  sort_gemm1<<<NBUCK + (GB - GH), 256, 0, stream>>>(pairs, gcur, row_start, deg, sorted_src,
                                                    x, W1, as1, ad1, h16, s_src, s_dst);

  // ---- layer 1 aggregate ----
  agg_kernel<<<AGG_BLOCKS, 256, 0, stream>>>(sorted_src, row_start, deg, s_src, s_dst,
                                             h16, b1, A);
  // ---- layer 2 ----
  gemm_feat<<<GB, 256, 0, stream>>>(A, W2, as2, ad2, h16, s_src, s_dst, 1);
  agg_kernel<<<AGG_BLOCKS, 256, 0, stream>>>(sorted_src, row_start, deg, s_src, s_dst,
                                             h16, b2, B);
  // ---- layer 3 ----
  gemm_feat<<<GB, 256, 0, stream>>>(B, W3, as3, ad3, h16, s_src, s_dst, 1);
  agg_kernel<<<AGG_BLOCKS, 256, 0, stream>>>(sorted_src, row_start, deg, s_src, s_dst,
                                             h16, b3, out);
}